// Round 1
// baseline (1289.943 us; speedup 1.0000x reference)
//
#include <hip/hip_runtime.h>

// SparseGlobalPool: segment-mean of features [N, C=128] over batch_ids in [0, B=32).
// out[b][c] = mean of features[i][c] where batch_ids[i]==b, 0 if empty.
//
// ws layout: float sums[B*C] ; unsigned counts[B]   (4128 dwords = 16.5 KB)

constexpr int CH = 128;     // channels (validated from in_sizes at launch)
constexpr int BATCH = 32;   // segments (validated from out_size / CH)

__global__ __launch_bounds__(512) void sgp_zero(float* ws, int n) {
    int i = blockIdx.x * blockDim.x + threadIdx.x;
    if (i < n) ws[i] = 0.0f;   // bit-pattern 0 also zeroes the uint counts
}

__global__ __launch_bounds__(512) void sgp_accum(const float4* __restrict__ feat,
                                                 const int* __restrict__ bid,
                                                 float* __restrict__ gsum,
                                                 unsigned int* __restrict__ gcnt,
                                                 int N) {
    // acc[j][b][lane] accumulates features[.][lane*4 + j] for batch b.
    // Within a 32-lane row-group, lanes hit 32 distinct banks (stride 33 words, +1 pad).
    __shared__ float acc[4][BATCH][33];
    __shared__ unsigned int cnt[BATCH];

    for (int i = threadIdx.x; i < 4 * BATCH * 33; i += 512)
        (&acc[0][0][0])[i] = 0.0f;
    if (threadIdx.x < BATCH) cnt[threadIdx.x] = 0u;
    __syncthreads();

    const int lane = threadIdx.x & 31;
    const int grp  = threadIdx.x >> 5;         // 0..15 row-groups per block
    const int step = gridDim.x * 32;           // rows consumed per sweep (16 grp x 2 rows)

    int base = blockIdx.x * 32;
    // full sweeps: block covers rows [base, base+32)
    for (; base + 32 <= N; base += step) {
        const int r0 = base + grp;
        const int r1 = base + grp + 16;
        // issue all global loads first (memory ILP)
        const float4 v0 = feat[r0 * 32 + lane];
        const float4 v1 = feat[r1 * 32 + lane];
        const int b0 = bid[r0];
        const int b1 = bid[r1];

        atomicAdd(&acc[0][b0][lane], v0.x);
        atomicAdd(&acc[1][b0][lane], v0.y);
        atomicAdd(&acc[2][b0][lane], v0.z);
        atomicAdd(&acc[3][b0][lane], v0.w);
        if (lane == 0) atomicAdd(&cnt[b0], 1u);

        atomicAdd(&acc[0][b1][lane], v1.x);
        atomicAdd(&acc[1][b1][lane], v1.y);
        atomicAdd(&acc[2][b1][lane], v1.z);
        atomicAdd(&acc[3][b1][lane], v1.w);
        if (lane == 0) atomicAdd(&cnt[b1], 1u);
    }
    // tail (N not multiple of 32*grid): guarded
    if (base < N) {
        const int r0 = base + grp;
        const int r1 = base + grp + 16;
        if (r0 < N) {
            const float4 v0 = feat[r0 * 32 + lane];
            const int b0 = bid[r0];
            atomicAdd(&acc[0][b0][lane], v0.x);
            atomicAdd(&acc[1][b0][lane], v0.y);
            atomicAdd(&acc[2][b0][lane], v0.z);
            atomicAdd(&acc[3][b0][lane], v0.w);
            if (lane == 0) atomicAdd(&cnt[b0], 1u);
        }
        if (r1 < N) {
            const float4 v1 = feat[r1 * 32 + lane];
            const int b1 = bid[r1];
            atomicAdd(&acc[0][b1][lane], v1.x);
            atomicAdd(&acc[1][b1][lane], v1.y);
            atomicAdd(&acc[2][b1][lane], v1.z);
            atomicAdd(&acc[3][b1][lane], v1.w);
            if (lane == 0) atomicAdd(&cnt[b1], 1u);
        }
    }
    __syncthreads();

    // flush block partials: one hardware fp atomic per (b,c), plus counts
    for (int idx = threadIdx.x; idx < BATCH * CH; idx += 512) {
        const int b = idx >> 7;          // idx / 128
        const int c = idx & 127;         // idx % 128
        const float v = acc[c & 3][b][c >> 2];
        unsafeAtomicAdd(&gsum[idx], v);
    }
    if (threadIdx.x < BATCH) atomicAdd(&gcnt[threadIdx.x], cnt[threadIdx.x]);
}

__global__ __launch_bounds__(256) void sgp_final(const float* __restrict__ gsum,
                                                 const unsigned int* __restrict__ gcnt,
                                                 float* __restrict__ out) {
    int idx = blockIdx.x * blockDim.x + threadIdx.x;
    if (idx < BATCH * CH) {
        const unsigned int c = gcnt[idx >> 7];
        out[idx] = (c > 0u) ? gsum[idx] / (float)c : 0.0f;
    }
}

extern "C" void kernel_launch(void* const* d_in, const int* in_sizes, int n_in,
                              void* d_out, int out_size, void* d_ws, size_t ws_size,
                              hipStream_t stream) {
    const float4* feat = (const float4*)d_in[0];
    const int* bid     = (const int*)d_in[1];
    // d_in[2] = batch_size scalar on device; B fixed at 32 (== out_size / CH)
    const int N = in_sizes[1];

    float* gsum        = (float*)d_ws;
    unsigned int* gcnt = (unsigned int*)((char*)d_ws + BATCH * CH * sizeof(float));

    const int ws_dwords = BATCH * CH + BATCH;  // 4128
    sgp_zero<<<(ws_dwords + 511) / 512, 512, 0, stream>>>((float*)d_ws, ws_dwords);

    sgp_accum<<<1024, 512, 0, stream>>>(feat, bid, gsum, gcnt, N);

    sgp_final<<<(BATCH * CH + 255) / 256, 256, 0, stream>>>(gsum, gcnt, (float*)d_out);
}

// Round 2
// 1287.065 us; speedup vs baseline: 1.0022x; 1.0022x over previous
//
#include <hip/hip_runtime.h>

// SparseGlobalPool: segment-mean of features [N, C=128] over batch_ids in [0, B=32).
// out[b][c] = mean of features[i][c] where batch_ids[i]==b, 0 if empty.
//
// ws layout: float sums[B*C] ; unsigned counts[B]   (4128 dwords = 16.5 KB)
//
// Round-1 lesson: HIP's safe atomicAdd(float*) on LDS compiles to a CAS retry
// loop (~120cyc/attempt, retry storms under 32-way segment contention) ->
// 1285us at 1% VALUBusy. unsafeAtomicAdd emits native no-return ds_add_f32.

constexpr int CH = 128;     // channels
constexpr int BATCH = 32;   // segments

__global__ __launch_bounds__(512) void sgp_zero(float* ws, int n) {
    int i = blockIdx.x * blockDim.x + threadIdx.x;
    if (i < n) ws[i] = 0.0f;   // bit-pattern 0 also zeroes the uint counts
}

__global__ __launch_bounds__(512) void sgp_accum(const float4* __restrict__ feat,
                                                 const int* __restrict__ bid,
                                                 float* __restrict__ gsum,
                                                 unsigned int* __restrict__ gcnt,
                                                 int N) {
    // acc[j][b][lane]: bank = (b + lane) % 32 (stride 33, 4224*32 % 32 == 0)
    // -> each 32-lane group hits 32 distinct banks; the wave's 2 groups alias
    // 2-way which is free (m136).
    __shared__ float acc[4][BATCH][33];
    __shared__ unsigned int cnt[BATCH];

    for (int i = threadIdx.x; i < 4 * BATCH * 33; i += 512)
        (&acc[0][0][0])[i] = 0.0f;
    if (threadIdx.x < BATCH) cnt[threadIdx.x] = 0u;
    __syncthreads();

    const int lane = threadIdx.x & 31;
    const int grp  = threadIdx.x >> 5;         // 0..15 row-groups per block
    const int step = gridDim.x * 64;           // rows consumed per sweep (16 grp x 4 rows)

    int base = blockIdx.x * 64;
    for (; base + 64 <= N; base += step) {
        const int r0 = base + grp;
        const int r1 = r0 + 16;
        const int r2 = r0 + 32;
        const int r3 = r0 + 48;
        // issue all global loads first (4 rows in flight per thread)
        const float4 v0 = feat[r0 * 32 + lane];
        const float4 v1 = feat[r1 * 32 + lane];
        const float4 v2 = feat[r2 * 32 + lane];
        const float4 v3 = feat[r3 * 32 + lane];
        const int b0 = bid[r0];
        const int b1 = bid[r1];
        const int b2 = bid[r2];
        const int b3 = bid[r3];

        unsafeAtomicAdd(&acc[0][b0][lane], v0.x);
        unsafeAtomicAdd(&acc[1][b0][lane], v0.y);
        unsafeAtomicAdd(&acc[2][b0][lane], v0.z);
        unsafeAtomicAdd(&acc[3][b0][lane], v0.w);
        unsafeAtomicAdd(&acc[0][b1][lane], v1.x);
        unsafeAtomicAdd(&acc[1][b1][lane], v1.y);
        unsafeAtomicAdd(&acc[2][b1][lane], v1.z);
        unsafeAtomicAdd(&acc[3][b1][lane], v1.w);
        unsafeAtomicAdd(&acc[0][b2][lane], v2.x);
        unsafeAtomicAdd(&acc[1][b2][lane], v2.y);
        unsafeAtomicAdd(&acc[2][b2][lane], v2.z);
        unsafeAtomicAdd(&acc[3][b2][lane], v2.w);
        unsafeAtomicAdd(&acc[0][b3][lane], v3.x);
        unsafeAtomicAdd(&acc[1][b3][lane], v3.y);
        unsafeAtomicAdd(&acc[2][b3][lane], v3.z);
        unsafeAtomicAdd(&acc[3][b3][lane], v3.w);
        if (lane == 0) {
            atomicAdd(&cnt[b0], 1u);
            atomicAdd(&cnt[b1], 1u);
            atomicAdd(&cnt[b2], 1u);
            atomicAdd(&cnt[b3], 1u);
        }
    }
    // tail: per-row guards
    if (base < N) {
        #pragma unroll
        for (int k = 0; k < 4; ++k) {
            const int r = base + grp + 16 * k;
            if (r < N) {
                const float4 v = feat[r * 32 + lane];
                const int b = bid[r];
                unsafeAtomicAdd(&acc[0][b][lane], v.x);
                unsafeAtomicAdd(&acc[1][b][lane], v.y);
                unsafeAtomicAdd(&acc[2][b][lane], v.z);
                unsafeAtomicAdd(&acc[3][b][lane], v.w);
                if (lane == 0) atomicAdd(&cnt[b], 1u);
            }
        }
    }
    __syncthreads();

    // flush block partials: one hardware fp atomic per (b,c), plus counts
    for (int idx = threadIdx.x; idx < BATCH * CH; idx += 512) {
        const int b = idx >> 7;          // idx / 128
        const int c = idx & 127;         // idx % 128
        const float v = acc[c & 3][b][c >> 2];
        unsafeAtomicAdd(&gsum[idx], v);
    }
    if (threadIdx.x < BATCH) atomicAdd(&gcnt[threadIdx.x], cnt[threadIdx.x]);
}

__global__ __launch_bounds__(256) void sgp_final(const float* __restrict__ gsum,
                                                 const unsigned int* __restrict__ gcnt,
                                                 float* __restrict__ out) {
    int idx = blockIdx.x * blockDim.x + threadIdx.x;
    if (idx < BATCH * CH) {
        const unsigned int c = gcnt[idx >> 7];
        out[idx] = (c > 0u) ? gsum[idx] / (float)c : 0.0f;
    }
}

extern "C" void kernel_launch(void* const* d_in, const int* in_sizes, int n_in,
                              void* d_out, int out_size, void* d_ws, size_t ws_size,
                              hipStream_t stream) {
    const float4* feat = (const float4*)d_in[0];
    const int* bid     = (const int*)d_in[1];
    const int N = in_sizes[1];

    float* gsum        = (float*)d_ws;
    unsigned int* gcnt = (unsigned int*)((char*)d_ws + BATCH * CH * sizeof(float));

    const int ws_dwords = BATCH * CH + BATCH;  // 4128
    sgp_zero<<<(ws_dwords + 511) / 512, 512, 0, stream>>>((float*)d_ws, ws_dwords);

    sgp_accum<<<1024, 512, 0, stream>>>(feat, bid, gsum, gcnt, N);

    sgp_final<<<(BATCH * CH + 255) / 256, 256, 0, stream>>>(gsum, gcnt, (float*)d_out);
}

// Round 4
// 1056.751 us; speedup vs baseline: 1.2207x; 1.2179x over previous
//
#include <hip/hip_runtime.h>

// SparseGlobalPool: segment-mean of features [N, C=128] over batch_ids in [0, B=32).
// out[b][c] = mean of features[i][c] where batch_ids[i]==b, 0 if empty.
//
// ws layout: float sums[B*C] ; unsigned counts[B]   (4128 dwords = 16.5 KB)
//
// Round-1/2 lesson: LDS float atomics (ds_add_f32) are the bottleneck —
// both safe and unsafe atomicAdd emit the same op and the LDS atomic pipe
// serialized at ~200cyc/wave-op under 32-segment contention (1285us @ 0.8%
// VALUBusy, 5% HBM). This version has ZERO atomics in the streaming loop:
// one wave owns a whole row (float2/lane), so batch_id is wave-uniform ->
// scalar 32-way switch into 32 named per-thread register accumulators.
// (Round 3: fixed c2 name collision with the c0..c31 count registers.)

constexpr int CH = 128;     // channels
constexpr int BATCH = 32;   // segments

#define SGP_FOREACH(X) \
    X(0) X(1) X(2) X(3) X(4) X(5) X(6) X(7) \
    X(8) X(9) X(10) X(11) X(12) X(13) X(14) X(15) \
    X(16) X(17) X(18) X(19) X(20) X(21) X(22) X(23) \
    X(24) X(25) X(26) X(27) X(28) X(29) X(30) X(31)

#define SGP_FOREACH2(X, A) \
    X(0,A) X(1,A) X(2,A) X(3,A) X(4,A) X(5,A) X(6,A) X(7,A) \
    X(8,A) X(9,A) X(10,A) X(11,A) X(12,A) X(13,A) X(14,A) X(15,A) \
    X(16,A) X(17,A) X(18,A) X(19,A) X(20,A) X(21,A) X(22,A) X(23,A) \
    X(24,A) X(25,A) X(26,A) X(27,A) X(28,A) X(29,A) X(30,A) X(31,A)

__global__ __launch_bounds__(512) void sgp_zero(float* ws, int n) {
    int i = blockIdx.x * blockDim.x + threadIdx.x;
    if (i < n) ws[i] = 0.0f;   // bit-pattern 0 also zeroes the uint counts
}

__global__ __launch_bounds__(512) void sgp_accum(const float2* __restrict__ feat2,
                                                 const int* __restrict__ bid,
                                                 float* __restrict__ gsum,
                                                 unsigned int* __restrict__ gcnt,
                                                 int N) {
    const int lane = threadIdx.x & 63;
    // wave-uniform wave id (SGPR) -> row indices are scalar -> bid loads scalar
    const int w  = __builtin_amdgcn_readfirstlane(
                       (int)(blockIdx.x * (blockDim.x >> 6) + (threadIdx.x >> 6)));
    const int NW = gridDim.x * (blockDim.x >> 6);   // total waves

    // 32 named register accumulators (float2 = this lane's 2 channels) + counts.
    // Named scalars with static indices only -> guaranteed VGPRs, no scratch.
#define SGP_DECL(k) float2 a##k = {0.0f, 0.0f}; unsigned c##k = 0u;
    SGP_FOREACH(SGP_DECL)
#undef SGP_DECL

    // uniform (scalar) 32-way dispatch: 2 v_add_f32 + 1 v_add_u32 per row
#define SGP_CASE(k, V) case k: a##k.x += (V).x; a##k.y += (V).y; c##k += 1u; break;
#define SGP_ACC(B, V) switch (B) { SGP_FOREACH2(SGP_CASE, V) default: break; }

    int base = w * 4;
    const int stride = NW * 4;
    for (; base + 4 <= N; base += stride) {
        // scalar batch-id loads (wave-uniform)
        const int b0 = __builtin_amdgcn_readfirstlane(bid[base + 0]);
        const int b1 = __builtin_amdgcn_readfirstlane(bid[base + 1]);
        const int b2 = __builtin_amdgcn_readfirstlane(bid[base + 2]);
        const int b3 = __builtin_amdgcn_readfirstlane(bid[base + 3]);
        // 4 rows in flight: 4 x dwordx2, 512B/wave each, 2KB contiguous total
        const float2 v0 = feat2[(size_t)(base + 0) * 64 + lane];
        const float2 v1 = feat2[(size_t)(base + 1) * 64 + lane];
        const float2 v2 = feat2[(size_t)(base + 2) * 64 + lane];
        const float2 v3 = feat2[(size_t)(base + 3) * 64 + lane];

        SGP_ACC(b0, v0)
        SGP_ACC(b1, v1)
        SGP_ACC(b2, v2)
        SGP_ACC(b3, v3)
    }
    // tail rows (only the few waves whose last chunk straddles N)
    if (base < N) {
        for (int r = base; r < N; ++r) {
            const int b = __builtin_amdgcn_readfirstlane(bid[r]);
            const float2 v = feat2[(size_t)r * 64 + lane];
            SGP_ACC(b, v)
        }
    }

    // flush: per wave, 64 global fp atomics (hardware global_atomic_add_f32)
    // + 32 count atomics from lane 0. ~4096 waves -> <=4096 RMWs per address.
    const int ch2 = lane << 1;
#define SGP_FLUSH(k) \
    unsafeAtomicAdd(&gsum[k * CH + ch2], a##k.x); \
    unsafeAtomicAdd(&gsum[k * CH + ch2 + 1], a##k.y); \
    if (lane == 0) atomicAdd(&gcnt[k], c##k);
    SGP_FOREACH(SGP_FLUSH)
#undef SGP_FLUSH
}

__global__ __launch_bounds__(256) void sgp_final(const float* __restrict__ gsum,
                                                 const unsigned int* __restrict__ gcnt,
                                                 float* __restrict__ out) {
    int idx = blockIdx.x * blockDim.x + threadIdx.x;
    if (idx < BATCH * CH) {
        const unsigned int c = gcnt[idx >> 7];
        out[idx] = (c > 0u) ? gsum[idx] / (float)c : 0.0f;
    }
}

extern "C" void kernel_launch(void* const* d_in, const int* in_sizes, int n_in,
                              void* d_out, int out_size, void* d_ws, size_t ws_size,
                              hipStream_t stream) {
    const float2* feat2 = (const float2*)d_in[0];
    const int* bid      = (const int*)d_in[1];
    const int N = in_sizes[1];

    float* gsum        = (float*)d_ws;
    unsigned int* gcnt = (unsigned int*)((char*)d_ws + BATCH * CH * sizeof(float));

    const int ws_dwords = BATCH * CH + BATCH;  // 4128
    sgp_zero<<<(ws_dwords + 511) / 512, 512, 0, stream>>>((float*)d_ws, ws_dwords);

    // 512 blocks x 512 thr = 4096 waves = 16 waves/CU (2 blocks/CU), each wave
    // owns whole rows (float2/lane), 4 rows in flight -> ~32KB in-flight/CU.
    sgp_accum<<<512, 512, 0, stream>>>(feat2, bid, gsum, gcnt, N);

    sgp_final<<<(BATCH * CH + 255) / 256, 256, 0, stream>>>(gsum, gcnt, (float*)d_out);
}